// Round 1
// baseline (933.223 us; speedup 1.0000x reference)
//
#include <hip/hip_runtime.h>

#define NN 50000
#define NE 800000
#define NEP (NE + 256)

// ws element offsets (4-byte units), all 64-element aligned
#define O_DEGIN   0
#define O_DEGOUT  50048
#define O_RELCNT  100096
#define O_RELBASE 100160
#define O_RELCUR  100224
#define O_ROWPTR  100288
#define O_CURSOR  150336
#define O_PERM    200384
#define O_ELIST   1000640
#define O_PF      1800640
#define O_PD      8200640
#define O_ZN      14600640
#define O_LOOPB   14650688
#define O_EZ      16250688
#define O_EZM     17050944
#define O_HPRE    42659136
#define O_H1      44259136
// total = 45859136 elems = ~183.5 MB

// ---------------- setup kernels ----------------

__global__ __launch_bounds__(256) void k_deg(const int* __restrict__ src,
                                             const int* __restrict__ dst,
                                             const int* __restrict__ eid,
                                             int* degin, int* degout, int* relcnt) {
    __shared__ int hcnt[4];
    int t = threadIdx.x;
    if (t < 4) hcnt[t] = 0;
    __syncthreads();
    int e = blockIdx.x * 256 + t;
    if (e < NE) {
        atomicAdd(&degin[dst[e]], 1);
        atomicAdd(&degout[src[e]], 1);
        atomicAdd(&hcnt[eid[e]], 1);
    }
    __syncthreads();
    if (t < 4 && hcnt[t]) atomicAdd(&relcnt[t], hcnt[t]);
}

__global__ __launch_bounds__(1024) void k_scan(const int* __restrict__ degin,
                                               const int* __restrict__ relcnt,
                                               int* rowptr, int* cursor,
                                               int* relbase, int* relcur) {
    __shared__ int sb[1024];
    int t = threadIdx.x;
    int carry = 0;
    for (int b0 = 0; b0 < NN; b0 += 4096) {
        int i0 = b0 + t * 4;
        int v0 = 0, v1 = 0, v2 = 0, v3 = 0;
        if (i0 + 3 < NN) {
            v0 = degin[i0]; v1 = degin[i0 + 1]; v2 = degin[i0 + 2]; v3 = degin[i0 + 3];
        } else {
            if (i0     < NN) v0 = degin[i0];
            if (i0 + 1 < NN) v1 = degin[i0 + 1];
            if (i0 + 2 < NN) v2 = degin[i0 + 2];
            if (i0 + 3 < NN) v3 = degin[i0 + 3];
        }
        int s = v0 + v1 + v2 + v3;
        sb[t] = s;
        __syncthreads();
        for (int off = 1; off < 1024; off <<= 1) {
            int x = (t >= off) ? sb[t - off] : 0;
            __syncthreads();
            sb[t] += x;
            __syncthreads();
        }
        int excl = carry + sb[t] - s;
        int tot = sb[1023];
        if (i0     < NN) { rowptr[i0]     = excl; cursor[i0]     = excl; } excl += v0;
        if (i0 + 1 < NN) { rowptr[i0 + 1] = excl; cursor[i0 + 1] = excl; } excl += v1;
        if (i0 + 2 < NN) { rowptr[i0 + 2] = excl; cursor[i0 + 2] = excl; } excl += v2;
        if (i0 + 3 < NN) { rowptr[i0 + 3] = excl; cursor[i0 + 3] = excl; }
        carry += tot;
        __syncthreads();
    }
    if (t == 0) {
        rowptr[NN] = carry;
        int b = 0;
        for (int r = 0; r < 4; r++) {
            relbase[r] = b;
            relcur[r] = b;
            b = (b + relcnt[r] + 63) & ~63;  // 64-align buckets -> relation-uniform waves
        }
    }
}

__global__ __launch_bounds__(256) void k_scatter(const int* __restrict__ dst,
                                                 const int* __restrict__ eid,
                                                 int* cursor, int* relcur,
                                                 int* perm, int* elist) {
    __shared__ int cnt[4];
    __shared__ int base[4];
    int t = threadIdx.x;
    if (t < 4) cnt[t] = 0;
    __syncthreads();
    int e = blockIdx.x * 256 + t;
    int r = 0, rank = 0;
    bool valid = e < NE;
    if (valid) {
        r = eid[e];
        rank = atomicAdd(&cnt[r], 1);
    }
    __syncthreads();
    if (t < 4) base[t] = cnt[t] ? atomicAdd(&relcur[t], cnt[t]) : 0;
    __syncthreads();
    if (valid) {
        int j = base[r] + rank;
        perm[j] = e;                       // perm: bucketed-by-relation edge order
        int slot = atomicAdd(&cursor[dst[e]], 1);
        elist[slot] = j;                   // per-dst list stores perm-slot j
    }
}

// ---------------- per-layer kernels ----------------

// One thread per node: Pf[r][n][:], Pd[r][n][:], zn[n], loopb[n][:]
__global__ __launch_bounds__(256) void k_nodeproj(const float* __restrict__ feat,
                                                  const float* __restrict__ nfeat,
                                                  const float* __restrict__ Wr,
                                                  const float* __restrict__ attw,
                                                  const float* __restrict__ lw,
                                                  const int* __restrict__ degout,
                                                  float* __restrict__ Pf,
                                                  float* __restrict__ Pd,
                                                  float* __restrict__ zn,
                                                  float* __restrict__ loopb) {
    int n = blockIdx.x * 256 + threadIdx.x;
    if (n >= NN) return;
    int dg = degout[n];
    float sc0 = rsqrtf((float)(dg > 1 ? dg : 1));
    const float* fin = feat + (size_t)n * 32;
    const float* nin = nfeat + (size_t)n * 32;
    float acc[32];

    for (int r = 0; r < 4; r++) {
        const float* W = Wr + (size_t)r * 96 * 32;  // rows 0:32 (feat part)
#pragma unroll
        for (int i = 0; i < 32; i++) acc[i] = 0.f;
        for (int k4 = 0; k4 < 32; k4 += 4) {
            float4 f4 = *(const float4*)&fin[k4];
            f4.x *= sc0; f4.y *= sc0; f4.z *= sc0; f4.w *= sc0;
            const float* Wk = W + k4 * 32;
#pragma unroll
            for (int i = 0; i < 32; i++) acc[i] += f4.x * Wk[i];
#pragma unroll
            for (int i = 0; i < 32; i++) acc[i] += f4.y * Wk[32 + i];
#pragma unroll
            for (int i = 0; i < 32; i++) acc[i] += f4.z * Wk[64 + i];
#pragma unroll
            for (int i = 0; i < 32; i++) acc[i] += f4.w * Wk[96 + i];
        }
        float* po = Pf + ((size_t)r * NN + n) * 32;
#pragma unroll
        for (int i = 0; i < 32; i += 4)
            *(float4*)&po[i] = make_float4(acc[i], acc[i + 1], acc[i + 2], acc[i + 3]);

        const float* W2 = W + 64 * 32;              // rows 64:96 (dst part)
#pragma unroll
        for (int i = 0; i < 32; i++) acc[i] = 0.f;
        for (int k4 = 0; k4 < 32; k4 += 4) {
            float4 f4 = *(const float4*)&nin[k4];
            const float* Wk = W2 + k4 * 32;
#pragma unroll
            for (int i = 0; i < 32; i++) acc[i] += f4.x * Wk[i];
#pragma unroll
            for (int i = 0; i < 32; i++) acc[i] += f4.y * Wk[32 + i];
#pragma unroll
            for (int i = 0; i < 32; i++) acc[i] += f4.z * Wk[64 + i];
#pragma unroll
            for (int i = 0; i < 32; i++) acc[i] += f4.w * Wk[96 + i];
        }
        float* qo = Pd + ((size_t)r * NN + n) * 32;
#pragma unroll
        for (int i = 0; i < 32; i += 4)
            *(float4*)&qo[i] = make_float4(acc[i], acc[i + 1], acc[i + 2], acc[i + 3]);
    }

    // loopb = node_feat @ loop_w
#pragma unroll
    for (int i = 0; i < 32; i++) acc[i] = 0.f;
    for (int k4 = 0; k4 < 32; k4 += 4) {
        float4 f4 = *(const float4*)&nin[k4];
        const float* Wk = lw + k4 * 32;
#pragma unroll
        for (int i = 0; i < 32; i++) acc[i] += f4.x * Wk[i];
#pragma unroll
        for (int i = 0; i < 32; i++) acc[i] += f4.y * Wk[32 + i];
#pragma unroll
        for (int i = 0; i < 32; i++) acc[i] += f4.z * Wk[64 + i];
#pragma unroll
        for (int i = 0; i < 32; i++) acc[i] += f4.w * Wk[96 + i];
    }
    float* lo = loopb + (size_t)n * 32;
#pragma unroll
    for (int i = 0; i < 32; i += 4)
        *(float4*)&lo[i] = make_float4(acc[i], acc[i + 1], acc[i + 2], acc[i + 3]);

    // zn = node_feat . attn_w[0:32]
    float z = 0.f;
    for (int k = 0; k < 32; k++) z += nin[k] * attw[k];
    zn[n] = z;
}

// One thread per perm-slot j: m, z, ez; writes ez[j], ezm[j][:]
__global__ __launch_bounds__(256) void k_edge(const int* __restrict__ perm,
                                              const int* __restrict__ src,
                                              const int* __restrict__ dst,
                                              const float* __restrict__ efeat,
                                              const float* __restrict__ Wr,
                                              const float* __restrict__ attw,
                                              const float* __restrict__ Pf,
                                              const float* __restrict__ Pd,
                                              const float* __restrict__ zn,
                                              const int* __restrict__ relbase,
                                              float* __restrict__ ez,
                                              float* __restrict__ ezm) {
    int j = blockIdx.x * 256 + threadIdx.x;
    // relation is constant over each 64-aligned slot range -> wave-uniform
    int j0 = j & ~63;
    int b1 = relbase[1], b2 = relbase[2], b3 = relbase[3];
    int r = (j0 >= b3) ? 3 : ((j0 >= b2) ? 2 : ((j0 >= b1) ? 1 : 0));
    r = __builtin_amdgcn_readfirstlane(r);   // force scalar -> s_load for W

    int e = perm[j];
    bool valid = e >= 0;
    int el = valid ? e : 0;
    int s = src[el], d = dst[el];

    const float* pf = Pf + ((size_t)r * NN + s) * 32;
    const float* pd = Pd + ((size_t)r * NN + d) * 32;
    float m[32];
#pragma unroll
    for (int i = 0; i < 32; i += 4) {
        float4 a = *(const float4*)&pf[i];
        float4 b = *(const float4*)&pd[i];
        m[i] = a.x + b.x; m[i + 1] = a.y + b.y; m[i + 2] = a.z + b.z; m[i + 3] = a.w + b.w;
    }

    const float* W = Wr + ((size_t)r * 96 + 32) * 32;  // rows 32:64 (edge part), uniform
    const float* efr = efeat + (size_t)el * 32;
    for (int k4 = 0; k4 < 32; k4 += 4) {
        float4 f4 = *(const float4*)&efr[k4];
        const float* Wk = W + k4 * 32;
#pragma unroll
        for (int i = 0; i < 32; i++) m[i] += f4.x * Wk[i];
#pragma unroll
        for (int i = 0; i < 32; i++) m[i] += f4.y * Wk[32 + i];
#pragma unroll
        for (int i = 0; i < 32; i++) m[i] += f4.z * Wk[64 + i];
#pragma unroll
        for (int i = 0; i < 32; i++) m[i] += f4.w * Wk[96 + i];
    }

    float q = zn[d];
#pragma unroll
    for (int i = 0; i < 32; i++) q += m[i] * attw[32 + i];
    float z = q > 0.f ? q : 0.01f * q;       // leaky_relu(0.01)
    float ezv = __expf(z);                   // softmax max-shift cancels; z is O(1)

    if (valid) {
        ez[j] = ezv;
        float* eo = ezm + (size_t)j * 32;
#pragma unroll
        for (int i = 0; i < 32; i += 4)
            *(float4*)&eo[i] = make_float4(ezv * m[i], ezv * m[i + 1], ezv * m[i + 2], ezv * m[i + 3]);
    }
}

// One wave per node: h = (sum ez*m)/(sum ez) + loopb, * deg_in^-1/2, + bias
__global__ __launch_bounds__(256) void k_agg(const int* __restrict__ rowptr,
                                             const int* __restrict__ elist,
                                             const float* __restrict__ ez,
                                             const float* __restrict__ ezm,
                                             const float* __restrict__ loopb,
                                             const float* __restrict__ hbias,
                                             float* __restrict__ hpre) {
    int wid = threadIdx.x >> 6;
    int n = blockIdx.x * 4 + wid;
    if (n >= NN) return;
    int lane = threadIdx.x & 63;
    int col = lane & 31, half = lane >> 5;
    int rp0 = rowptr[n];
    int deg = rowptr[n + 1] - rp0;
    float num = 0.f, den = 0.f;
    for (int t = half; t < deg; t += 2) {
        int jj = elist[rp0 + t];
        den += ez[jj];
        num += ezm[(size_t)jj * 32 + col];
    }
    num += __shfl_xor(num, 32);
    den += __shfl_xor(den, 32);
    float h = (deg > 0) ? num / den : 0.f;
    h += loopb[(size_t)n * 32 + col];
    h *= rsqrtf((float)(deg > 1 ? deg : 1));
    h += hbias[col];
    if (half == 0) hpre[(size_t)n * 32 + col] = h;
}

// One thread per node: AMRM + relu -> layer output
__global__ __launch_bounds__(256) void k_amrm(const float* __restrict__ hpre,
                                              const float* __restrict__ aW,
                                              const float* __restrict__ ab,
                                              const float* __restrict__ aa,
                                              float* __restrict__ out) {
    int n = blockIdx.x * 256 + threadIdx.x;
    if (n >= NN) return;
    const float* hp = hpre + (size_t)n * 32;

    float s[3];
#pragma unroll
    for (int l = 0; l < 3; l++) {
        float acc[32];
#pragma unroll
        for (int o = 0; o < 32; o++) acc[o] = ab[l * 32 + o];
        for (int h4 = 0; h4 < 32; h4 += 4) {
            float4 hv = *(const float4*)&hp[h4];
            const float* Wk = aW + ((size_t)l * 32 + h4) * 32;
#pragma unroll
            for (int o = 0; o < 32; o++) acc[o] += hv.x * Wk[o];
#pragma unroll
            for (int o = 0; o < 32; o++) acc[o] += hv.y * Wk[32 + o];
#pragma unroll
            for (int o = 0; o < 32; o++) acc[o] += hv.z * Wk[64 + o];
#pragma unroll
            for (int o = 0; o < 32; o++) acc[o] += hv.w * Wk[96 + o];
        }
        float sl = 0.f;
#pragma unroll
        for (int o = 0; o < 32; o++) {
            float lv = acc[o] > 0.f ? acc[o] : 0.f;
            sl += lv * aa[o];
        }
        s[l] = sl;
    }
    float mx = fmaxf(s[0], fmaxf(s[1], s[2]));
    float e0 = __expf(s[0] - mx), e1 = __expf(s[1] - mx), e2 = __expf(s[2] - mx);
    float inv = 1.f / (e0 + e1 + e2);
    float scl[3] = {e0 * inv, e1 * inv, e2 * inv};

    float outv[32];
#pragma unroll
    for (int o = 0; o < 32; o++) outv[o] = 0.f;
#pragma unroll
    for (int l = 0; l < 3; l++) {
        float acc[32];
#pragma unroll
        for (int o = 0; o < 32; o++) acc[o] = ab[l * 32 + o];
        for (int h4 = 0; h4 < 32; h4 += 4) {
            float4 hv = *(const float4*)&hp[h4];
            const float* Wk = aW + ((size_t)l * 32 + h4) * 32;
#pragma unroll
            for (int o = 0; o < 32; o++) acc[o] += hv.x * Wk[o];
#pragma unroll
            for (int o = 0; o < 32; o++) acc[o] += hv.y * Wk[32 + o];
#pragma unroll
            for (int o = 0; o < 32; o++) acc[o] += hv.z * Wk[64 + o];
#pragma unroll
            for (int o = 0; o < 32; o++) acc[o] += hv.w * Wk[96 + o];
        }
#pragma unroll
        for (int o = 0; o < 32; o++) {
            float lv = acc[o] > 0.f ? acc[o] : 0.f;
            outv[o] += scl[l] * lv;
        }
    }
    float* op = out + (size_t)n * 32;
#pragma unroll
    for (int o = 0; o < 32; o += 4) {
        float4 v = make_float4(fmaxf(outv[o], 0.f), fmaxf(outv[o + 1], 0.f),
                               fmaxf(outv[o + 2], 0.f), fmaxf(outv[o + 3], 0.f));
        *(float4*)&op[o] = v;
    }
}

// ---------------- host ----------------

static void launch_layer(const float* feat, const float* nf, const float* efeat,
                         const int* src, const int* dst,
                         const float* Wr, const float* attw, const float* lw,
                         const float* hb, const float* aW, const float* ab,
                         const float* aa, float* wsf, int* wsi, float* out,
                         hipStream_t stream) {
    k_nodeproj<<<196, 256, 0, stream>>>(feat, nf, Wr, attw, lw, wsi + O_DEGOUT,
                                        wsf + O_PF, wsf + O_PD, wsf + O_ZN, wsf + O_LOOPB);
    k_edge<<<NEP / 256, 256, 0, stream>>>(wsi + O_PERM, src, dst, efeat, Wr, attw,
                                          wsf + O_PF, wsf + O_PD, wsf + O_ZN,
                                          wsi + O_RELBASE, wsf + O_EZ, wsf + O_EZM);
    k_agg<<<12500, 256, 0, stream>>>(wsi + O_ROWPTR, wsi + O_ELIST, wsf + O_EZ,
                                     wsf + O_EZM, wsf + O_LOOPB, hb, wsf + O_HPRE);
    k_amrm<<<196, 256, 0, stream>>>(wsf + O_HPRE, aW, ab, aa, out);
}

extern "C" void kernel_launch(void* const* d_in, const int* in_sizes, int n_in,
                              void* d_out, int out_size, void* d_ws, size_t ws_size,
                              hipStream_t stream) {
    const float* x     = (const float*)d_in[0];
    const float* nfeat = (const float*)d_in[1];
    const float* efeat = (const float*)d_in[2];
    const int*   src   = (const int*)d_in[3];
    const int*   dst   = (const int*)d_in[4];
    const int*   eid   = (const int*)d_in[5];
    const float* Wr1   = (const float*)d_in[6];
    const float* attw1 = (const float*)d_in[7];
    const float* lw1   = (const float*)d_in[8];
    const float* hb1   = (const float*)d_in[9];
    const float* aW1   = (const float*)d_in[10];
    const float* ab1   = (const float*)d_in[11];
    const float* aa1   = (const float*)d_in[12];
    const float* Wr2   = (const float*)d_in[13];
    const float* attw2 = (const float*)d_in[14];
    const float* lw2   = (const float*)d_in[15];
    const float* hb2   = (const float*)d_in[16];
    const float* aW2   = (const float*)d_in[17];
    const float* ab2   = (const float*)d_in[18];
    const float* aa2   = (const float*)d_in[19];

    float* wsf = (float*)d_ws;
    int*   wsi = (int*)d_ws;
    float* out = (float*)d_out;

    // zero degree/relation counters; poison-fill perm with -1 (bucket padding)
    hipMemsetAsync(d_ws, 0, (size_t)O_ROWPTR * 4, stream);
    hipMemsetAsync((char*)d_ws + (size_t)O_PERM * 4, 0xFF, (size_t)NEP * 4, stream);

    k_deg<<<NE / 256, 256, 0, stream>>>(src, dst, eid, wsi + O_DEGIN, wsi + O_DEGOUT,
                                        wsi + O_RELCNT);
    k_scan<<<1, 1024, 0, stream>>>(wsi + O_DEGIN, wsi + O_RELCNT, wsi + O_ROWPTR,
                                   wsi + O_CURSOR, wsi + O_RELBASE, wsi + O_RELCUR);
    k_scatter<<<NE / 256, 256, 0, stream>>>(dst, eid, wsi + O_CURSOR, wsi + O_RELCUR,
                                            wsi + O_PERM, wsi + O_ELIST);

    // layer 1: feat = x, output -> h1 (ws)
    launch_layer(x, nfeat, efeat, src, dst, Wr1, attw1, lw1, hb1, aW1, ab1, aa1,
                 wsf, wsi, wsf + O_H1, stream);
    // layer 2: feat = h1, output -> d_out
    launch_layer(wsf + O_H1, nfeat, efeat, src, dst, Wr2, attw2, lw2, hb2, aW2, ab2, aa2,
                 wsf, wsi, out, stream);
}